// Round 9
// baseline (178.213 us; speedup 1.0000x reference)
//
#include <hip/hip_runtime.h>
#include <hip/hip_bf16.h>
#include <hip/hip_cooperative_groups.h>

namespace cg = cooperative_groups;

#define NN 50000
#define CH 64
#define NB 1563          // ceil(NN/32) coarse buckets of 32 nodes
#define NBLK 256         // blocks in cooperative CSR kernel (1 per CU)

// ---------- ws layout (bytes; ws is 256 MiB — plenty) ----------
// msgb      : [0, 6.4MB)               uint[NN*32] — bf16x2-packed x@Wn + bn
// sorted    : [12.8M, 16.0M)           int[E] packed (dst&31)<<16 | src, by bucket
// blockhist : [16.0M, +NBLK*NB*4)      int[NBLK][NB]
// btotal    : [18.0M, +6,252)          int[NB]
// bstart    : [18.1M, +6,256)          int[NB+1]

// ---------------- k_csr: cooperative hist -> scanA -> scanB -> scatter
__global__ __launch_bounds__(256) void k_csr(
    const int* __restrict__ rows, const int* __restrict__ cols,
    int* __restrict__ bh, int* __restrict__ btotal,
    int* __restrict__ bstart, int* __restrict__ sorted, int E)
{
    cg::grid_group grid = cg::this_grid();
    __shared__ int lh[NB];

    const int b = blockIdx.x, tid = threadIdx.x;
    const int lane = tid & 63, wid = tid >> 6;
    const int chunk = (E + NBLK - 1) / NBLK;
    const int beg = b * chunk;
    const int fin = min(beg + chunk, E);

    // ---- P1: per-block LDS histogram of dest buckets
    for (int k = tid; k < NB; k += 256) lh[k] = 0;
    __syncthreads();
    for (int i = beg + tid; i < fin; i += 256)
        atomicAdd(&lh[cols[i] >> 5], 1);
    __syncthreads();
    for (int k = tid; k < NB; k += 256) bh[b * NB + k] = lh[k];
    grid.sync();

    // ---- P2: per-bucket exclusive prefix over blocks (thread gk owns bucket)
    const int gk = b * 256 + tid;
    if (gk < NB) {
        int run = 0;
        for (int bb = 0; bb < NBLK; bb++) {
            const int t = bh[bb * NB + gk];
            bh[bb * NB + gk] = run;
            run += t;
        }
        btotal[gk] = run;
    }
    grid.sync();

    // ---- P3: block 0: bstart = exclusive_scan(btotal); bstart[NB] = E
    if (b == 0) {
        int carry = 0;
        for (int basei = 0; basei < NB; basei += 256) {
            const int i = basei + tid;
            const int v = (i < NB) ? btotal[i] : 0;
            int s = v;
#pragma unroll
            for (int d = 1; d < 64; d <<= 1) {
                int t = __shfl_up(s, d);
                if (lane >= d) s += t;
            }
            if (lane == 63) lh[wid] = s;        // 4 wave sums
            __syncthreads();
            if (tid == 0) {
                int a = 0;
#pragma unroll
                for (int k = 0; k < 4; k++) { int t = lh[k]; lh[k] = a; a += t; }
                lh[4] = a;
            }
            __syncthreads();
            if (i < NB) bstart[i] = carry + lh[wid] + (s - v);
            carry += lh[4];
            __syncthreads();
        }
        if (tid == 0) bstart[NB] = carry;       // = E
    }
    grid.sync();

    // ---- P4: scatter into bucket order (LDS atomics only)
    for (int k = tid; k < NB; k += 256)
        lh[k] = bstart[k] + bh[b * NB + k];
    __syncthreads();
    for (int i = beg + tid; i < fin; i += 256) {
        const int c = cols[i], r = rows[i];
        const int pos = atomicAdd(&lh[c >> 5], 1);
        sorted[pos] = ((c & 31) << 16) | r;     // src < 50000 < 2^16
    }
}

// ---------------- k_proj: h = x@Ws + bs -> out (f32),  m = x@Wn + bn -> msgb (bf16x2)
__global__ __launch_bounds__(256) void k_proj(
    const float* __restrict__ x,
    const float* __restrict__ Wself, const float* __restrict__ bself,
    const float* __restrict__ Wneigh, const float* __restrict__ bneigh,
    float* __restrict__ hout, unsigned int* __restrict__ mout)
{
    __shared__ float ws[CH * CH];
    __shared__ float wn[CH * CH];
    __shared__ float xs[32 * CH];
    const int tid = threadIdx.x;
    const int node0 = blockIdx.x * 32;

    for (int i = tid * 4; i < CH * CH; i += 256 * 4) {
        *(float4*)&ws[i] = *(const float4*)&Wself[i];
        *(float4*)&wn[i] = *(const float4*)&Wneigh[i];
    }
    for (int i = tid * 4; i < 32 * CH; i += 256 * 4) {
        const int nd = node0 + (i >> 6);
        float4 v = {0.f, 0.f, 0.f, 0.f};
        if (nd < NN) v = *(const float4*)&x[(size_t)nd * CH + (i & 63)];
        *(float4*)&xs[i] = v;
    }
    __syncthreads();

    const int lane = tid & 63;
    const int wave = tid >> 6;
    const int r0 = wave * 8;

    const float bsv = bself[lane];
    const float bnv = bneigh[lane];

    float accs[8], accn[8];
#pragma unroll
    for (int n = 0; n < 8; n++) { accs[n] = bsv; accn[n] = bnv; }

#pragma unroll 1
    for (int k4 = 0; k4 < CH; k4 += 4) {
        float4 xv[8];
#pragma unroll
        for (int n = 0; n < 8; n++)
            xv[n] = *(const float4*)&xs[(r0 + n) * CH + k4];
#pragma unroll
        for (int j = 0; j < 4; j++) {
            const float wsk = ws[(k4 + j) * CH + lane];
            const float wnk = wn[(k4 + j) * CH + lane];
#pragma unroll
            for (int n = 0; n < 8; n++) {
                const float xj = (j == 0) ? xv[n].x : (j == 1) ? xv[n].y
                               : (j == 2) ? xv[n].z : xv[n].w;
                accs[n] = fmaf(xj, wsk, accs[n]);
                accn[n] = fmaf(xj, wnk, accn[n]);
            }
        }
    }

#pragma unroll
    for (int n = 0; n < 8; n++) {
        const int nd = node0 + r0 + n;
        const float partner = __shfl_xor(accn[n], 1);
        if (nd < NN) {
            hout[(size_t)nd * CH + lane] = accs[n];
            if ((lane & 1) == 0) {
                __hip_bfloat162 p;
                p.x = __float2bfloat16(accn[n]);
                p.y = __float2bfloat16(partner);
                mout[(size_t)nd * 32 + (lane >> 1)] =
                    *reinterpret_cast<unsigned int*>(&p);
            }
        }
    }
}

// ---------------- k_gfin2: one block per bucket (32 nodes), 512 threads = 8 waves.
// Fine counting-sort in LDS, then bf16x2 gather (two edges per wave via the
// two 32-lane halves, 4-deep MLP per half); out = relu(h + sum).
__global__ __launch_bounds__(512) void k_gfin2(
    const unsigned int* __restrict__ mb, const int* __restrict__ bstart,
    const int* __restrict__ sorted, float* __restrict__ out)
{
    __shared__ int pairs[2048];
    __shared__ unsigned short srcs[2048];
    __shared__ int fh[32], foff[33], fcur[32];

    const int g = blockIdx.x;
    const int tid = threadIdx.x;
    const int lane = tid & 63, wave = tid >> 6;
    const int c2 = lane & 31;
    const int half = lane >> 5;
    const int base = bstart[g];
    const int ecnt = bstart[g + 1] - base;

    float accL[4], accH[4];
#pragma unroll
    for (int r = 0; r < 4; r++) { accL[r] = 0.f; accH[r] = 0.f; }

    for (int cb = 0; cb < ecnt; cb += 2048) {
        const int cn = min(2048, ecnt - cb);
        if (tid < 32) fh[tid] = 0;
        __syncthreads();
        for (int i = tid; i < cn; i += 512) {
            const int p = sorted[base + cb + i];
            pairs[i] = p;
            atomicAdd(&fh[p >> 16], 1);
        }
        __syncthreads();
        if (tid < 64) {
            const int v = (lane < 32) ? fh[lane] : 0;
            int s = v;
#pragma unroll
            for (int d = 1; d < 32; d <<= 1) {
                int t = __shfl_up(s, d);
                if (lane >= d) s += t;
            }
            if (lane < 32) { foff[lane] = s - v; fcur[lane] = s - v; }
            if (lane == 0) foff[32] = cn;
        }
        __syncthreads();
        for (int i = tid; i < cn; i += 512) {
            const int p = pairs[i];
            const int pos = atomicAdd(&fcur[p >> 16], 1);
            srcs[pos] = (unsigned short)(p & 0xFFFF);
        }
        __syncthreads();
#pragma unroll
        for (int r = 0; r < 4; r++) {
            const int nl = wave * 4 + r;
            const int j0 = foff[nl], j1 = foff[nl + 1];
            float l0 = 0.f, l1 = 0.f, l2 = 0.f, l3 = 0.f;
            float h0 = 0.f, h1 = 0.f, h2 = 0.f, h3 = 0.f;
            int j = j0 + half;
            for (; j + 6 < j1; j += 8) {
                const unsigned int v0 = mb[(int)srcs[j]     * 32 + c2];
                const unsigned int v1 = mb[(int)srcs[j + 2] * 32 + c2];
                const unsigned int v2 = mb[(int)srcs[j + 4] * 32 + c2];
                const unsigned int v3 = mb[(int)srcs[j + 6] * 32 + c2];
                l0 += __uint_as_float(v0 << 16); h0 += __uint_as_float(v0 & 0xFFFF0000u);
                l1 += __uint_as_float(v1 << 16); h1 += __uint_as_float(v1 & 0xFFFF0000u);
                l2 += __uint_as_float(v2 << 16); h2 += __uint_as_float(v2 & 0xFFFF0000u);
                l3 += __uint_as_float(v3 << 16); h3 += __uint_as_float(v3 & 0xFFFF0000u);
            }
            for (; j < j1; j += 2) {
                const unsigned int v = mb[(int)srcs[j] * 32 + c2];
                l0 += __uint_as_float(v << 16); h0 += __uint_as_float(v & 0xFFFF0000u);
            }
            accL[r] += (l0 + l1) + (l2 + l3);
            accH[r] += (h0 + h1) + (h2 + h3);
        }
        __syncthreads();
    }

#pragma unroll
    for (int r = 0; r < 4; r++) {
        accL[r] += __shfl_xor(accL[r], 32);
        accH[r] += __shfl_xor(accH[r], 32);
        const int nd = g * 32 + wave * 4 + r;
        if (nd < NN) {
            const int o = nd * CH + 2 * c2 + half;
            const float myv = half ? accH[r] : accL[r];
            out[o] = fmaxf(out[o] + myv, 0.f);
        }
    }
}

extern "C" void kernel_launch(void* const* d_in, const int* in_sizes, int n_in,
                              void* d_out, int out_size, void* d_ws, size_t ws_size,
                              hipStream_t stream)
{
    const float* x      = (const float*)d_in[0];
    const int*   edges  = (const int*)d_in[1];
    const float* Wself  = (const float*)d_in[2];
    const float* bself  = (const float*)d_in[3];
    const float* Wneigh = (const float*)d_in[4];
    const float* bneigh = (const float*)d_in[5];
    float* out = (float*)d_out;

    int E = in_sizes[1] / 2;
    const int* rows = edges;        // edge_index[0] (sources)
    const int* cols = edges + E;    // edge_index[1] (destinations)

    char* ws_base = (char*)d_ws;
    unsigned int* msgb = (unsigned int*)(ws_base);         // 6.4 MB (bf16x2)
    int*   sorted = (int*)(ws_base + 12800000);            // 3.2 MB
    int*   bh     = (int*)(ws_base + 16000000);            // NBLK*NB*4 = 1.6 MB
    int*   btotal = (int*)(ws_base + 18000000);            // 6,252
    int*   bstart = (int*)(ws_base + 18100000);            // 6,256 (NB+1)

    // cooperative CSR build: hist -> scanA -> scanB -> scatter in one launch
    void* csr_args[] = {(void*)&rows, (void*)&cols, (void*)&bh, (void*)&btotal,
                        (void*)&bstart, (void*)&sorted, (void*)&E};
    hipLaunchCooperativeKernel((const void*)k_csr, dim3(NBLK), dim3(256),
                               csr_args, 0, stream);

    const int bP = (NN + 31) / 32;   // 1563
    k_proj<<<bP, 256, 0, stream>>>(x, Wself, bself, Wneigh, bneigh, out, msgb);

    k_gfin2<<<NB, 512, 0, stream>>>(msgb, bstart, sorted, out);
}

// Round 10
// 95.447 us; speedup vs baseline: 1.8671x; 1.8671x over previous
//
#include <hip/hip_runtime.h>
#include <hip/hip_bf16.h>

#define NN 50000
#define CH 64
#define NB 1563          // ceil(NN/32) coarse buckets of 32 nodes
#define NBLK 128         // hist/scatter edge-chunk blocks

// ---------- ws layout (bytes; ws is 256 MiB) ----------
// msgb      : [0, 6.4MB)               uint[NN*32] — bf16x2-packed x@Wn + bn
// sorted    : [12.8M, 16.0M)           int[E] packed (dst&31)<<16 | src, by bucket
// blockhist : [16.0M, +800,256)        int[NBLK][NB]
// bstart    : [18.1M, +6,256)          int[NB+1]

// ---------------- k_histproj: blocks [0,NBLK) = dest-bucket histogram;
//                  blocks [NBLK, NBLK+1563) = dual projection (proven round-8 body)
__global__ __launch_bounds__(256) void k_histproj(
    const int* __restrict__ cols, int* __restrict__ bh, int E,
    const float* __restrict__ x,
    const float* __restrict__ Wself, const float* __restrict__ bself,
    const float* __restrict__ Wneigh, const float* __restrict__ bneigh,
    float* __restrict__ hout, unsigned int* __restrict__ mout)
{
    __shared__ float smem[2 * CH * CH + 32 * CH];   // 40 KB, overlaid per role
    const int tid = threadIdx.x;

    if (blockIdx.x < NBLK) {
        // ---- histogram role
        int* lh = (int*)smem;
        const int b = blockIdx.x;
        for (int k = tid; k < NB; k += 256) lh[k] = 0;
        __syncthreads();
        const int chunk = (E + NBLK - 1) / NBLK;
        const int beg = b * chunk;
        const int fin = min(beg + chunk, E);
        for (int i = beg + tid; i < fin; i += 256)
            atomicAdd(&lh[cols[i] >> 5], 1);
        __syncthreads();
        for (int k = tid; k < NB; k += 256) bh[b * NB + k] = lh[k];
        return;
    }

    // ---- projection role
    float* ws = smem;
    float* wn = smem + CH * CH;
    float* xs = smem + 2 * CH * CH;
    const int node0 = (blockIdx.x - NBLK) * 32;

    for (int i = tid * 4; i < CH * CH; i += 256 * 4) {
        *(float4*)&ws[i] = *(const float4*)&Wself[i];
        *(float4*)&wn[i] = *(const float4*)&Wneigh[i];
    }
    for (int i = tid * 4; i < 32 * CH; i += 256 * 4) {
        const int nd = node0 + (i >> 6);
        float4 v = {0.f, 0.f, 0.f, 0.f};
        if (nd < NN) v = *(const float4*)&x[(size_t)nd * CH + (i & 63)];
        *(float4*)&xs[i] = v;
    }
    __syncthreads();

    const int lane = tid & 63;
    const int wave = tid >> 6;
    const int r0 = wave * 8;

    const float bsv = bself[lane];
    const float bnv = bneigh[lane];

    float accs[8], accn[8];
#pragma unroll
    for (int n = 0; n < 8; n++) { accs[n] = bsv; accn[n] = bnv; }

#pragma unroll 1
    for (int k4 = 0; k4 < CH; k4 += 4) {
        float4 xv[8];
#pragma unroll
        for (int n = 0; n < 8; n++)
            xv[n] = *(const float4*)&xs[(r0 + n) * CH + k4];
#pragma unroll
        for (int j = 0; j < 4; j++) {
            const float wsk = ws[(k4 + j) * CH + lane];
            const float wnk = wn[(k4 + j) * CH + lane];
#pragma unroll
            for (int n = 0; n < 8; n++) {
                const float xj = (j == 0) ? xv[n].x : (j == 1) ? xv[n].y
                               : (j == 2) ? xv[n].z : xv[n].w;
                accs[n] = fmaf(xj, wsk, accs[n]);
                accn[n] = fmaf(xj, wnk, accn[n]);
            }
        }
    }

#pragma unroll
    for (int n = 0; n < 8; n++) {
        const int nd = node0 + r0 + n;
        const float partner = __shfl_xor(accn[n], 1);
        if (nd < NN) {
            hout[(size_t)nd * CH + lane] = accs[n];
            if ((lane & 1) == 0) {
                __hip_bfloat162 p;
                p.x = __float2bfloat16(accn[n]);
                p.y = __float2bfloat16(partner);
                mout[(size_t)nd * 32 + (lane >> 1)] =
                    *reinterpret_cast<unsigned int*>(&p);
            }
        }
    }
}

// ---------------- k_scanAB: ONE block, 1024 threads.
// Phase A: per-bucket exclusive prefix over the NBLK block-hists (in place),
// bucket totals kept in registers (2 buckets/thread).
// Phase B: block-wide exclusive scan of the 1563 totals -> bstart.
__global__ __launch_bounds__(1024) void k_scanAB(int* __restrict__ bh,
                                                 int* __restrict__ bstart)
{
    __shared__ int wsum[16];
    const int tid = threadIdx.x;
    const int lane = tid & 63, wid = tid >> 6;

    int tot[2];
#pragma unroll
    for (int rep = 0; rep < 2; rep++) {
        const int k = rep * 1024 + tid;
        int run = 0;
        if (k < NB) {
            for (int bb = 0; bb < NBLK; bb++) {
                const int t = bh[bb * NB + k];
                bh[bb * NB + k] = run;
                run += t;
            }
        }
        tot[rep] = run;
    }

    int carry = 0;
#pragma unroll
    for (int rep = 0; rep < 2; rep++) {
        const int v = tot[rep];
        int s = v;
#pragma unroll
        for (int d = 1; d < 64; d <<= 1) {
            int t = __shfl_up(s, d);
            if (lane >= d) s += t;
        }
        if (lane == 63) wsum[wid] = s;
        __syncthreads();
        if (wid == 0 && lane < 16) {
            int wscan = wsum[lane];
#pragma unroll
            for (int d = 1; d < 16; d <<= 1) {
                int t = __shfl_up(wscan, d);
                if (lane >= d) wscan += t;
            }
            wsum[lane] = wscan;
        }
        __syncthreads();
        const int wave_off = (wid == 0) ? 0 : wsum[wid - 1];
        const int k = rep * 1024 + tid;
        if (k < NB) bstart[k] = carry + wave_off + (s - v);
        carry += wsum[15];
        __syncthreads();
    }
    if (tid == 0) bstart[NB] = carry;     // = E
}

// ---------------- kc_scatter: place packed edges into bucket order; LDS atomics only
__global__ __launch_bounds__(256) void kc_scatter(
    const int* __restrict__ rows, const int* __restrict__ cols,
    const int* __restrict__ bh, const int* __restrict__ bstart,
    int* __restrict__ sorted, int E)
{
    __shared__ int lbase[NB];
    const int b = blockIdx.x, tid = threadIdx.x;
    for (int k = tid; k < NB; k += 256)
        lbase[k] = bstart[k] + bh[b * NB + k];
    __syncthreads();
    const int chunk = (E + NBLK - 1) / NBLK;
    const int beg = b * chunk;
    const int fin = min(beg + chunk, E);
    for (int i = beg + tid; i < fin; i += 256) {
        const int c = cols[i], r = rows[i];
        const int pos = atomicAdd(&lbase[c >> 5], 1);
        sorted[pos] = ((c & 31) << 16) | r;    // src < 50000 < 2^16
    }
}

// ---------------- k_gfin2: one block per bucket (32 nodes), 512 threads = 8 waves.
// Fine counting-sort in LDS, then bf16x2 gather (two edges per wave via the
// two 32-lane halves, 4-deep MLP per half); out = relu(h + sum).
__global__ __launch_bounds__(512) void k_gfin2(
    const unsigned int* __restrict__ mb, const int* __restrict__ bstart,
    const int* __restrict__ sorted, float* __restrict__ out)
{
    __shared__ int pairs[2048];
    __shared__ unsigned short srcs[2048];
    __shared__ int fh[32], foff[33], fcur[32];

    const int g = blockIdx.x;
    const int tid = threadIdx.x;
    const int lane = tid & 63, wave = tid >> 6;
    const int c2 = lane & 31;
    const int half = lane >> 5;
    const int base = bstart[g];
    const int ecnt = bstart[g + 1] - base;

    float accL[4], accH[4];
#pragma unroll
    for (int r = 0; r < 4; r++) { accL[r] = 0.f; accH[r] = 0.f; }

    for (int cb = 0; cb < ecnt; cb += 2048) {
        const int cn = min(2048, ecnt - cb);
        if (tid < 32) fh[tid] = 0;
        __syncthreads();
        for (int i = tid; i < cn; i += 512) {
            const int p = sorted[base + cb + i];
            pairs[i] = p;
            atomicAdd(&fh[p >> 16], 1);
        }
        __syncthreads();
        if (tid < 64) {
            const int v = (lane < 32) ? fh[lane] : 0;
            int s = v;
#pragma unroll
            for (int d = 1; d < 32; d <<= 1) {
                int t = __shfl_up(s, d);
                if (lane >= d) s += t;
            }
            if (lane < 32) { foff[lane] = s - v; fcur[lane] = s - v; }
            if (lane == 0) foff[32] = cn;
        }
        __syncthreads();
        for (int i = tid; i < cn; i += 512) {
            const int p = pairs[i];
            const int pos = atomicAdd(&fcur[p >> 16], 1);
            srcs[pos] = (unsigned short)(p & 0xFFFF);
        }
        __syncthreads();
#pragma unroll
        for (int r = 0; r < 4; r++) {
            const int nl = wave * 4 + r;
            const int j0 = foff[nl], j1 = foff[nl + 1];
            float l0 = 0.f, l1 = 0.f, l2 = 0.f, l3 = 0.f;
            float h0 = 0.f, h1 = 0.f, h2 = 0.f, h3 = 0.f;
            int j = j0 + half;
            for (; j + 6 < j1; j += 8) {
                const unsigned int v0 = mb[(int)srcs[j]     * 32 + c2];
                const unsigned int v1 = mb[(int)srcs[j + 2] * 32 + c2];
                const unsigned int v2 = mb[(int)srcs[j + 4] * 32 + c2];
                const unsigned int v3 = mb[(int)srcs[j + 6] * 32 + c2];
                l0 += __uint_as_float(v0 << 16); h0 += __uint_as_float(v0 & 0xFFFF0000u);
                l1 += __uint_as_float(v1 << 16); h1 += __uint_as_float(v1 & 0xFFFF0000u);
                l2 += __uint_as_float(v2 << 16); h2 += __uint_as_float(v2 & 0xFFFF0000u);
                l3 += __uint_as_float(v3 << 16); h3 += __uint_as_float(v3 & 0xFFFF0000u);
            }
            for (; j < j1; j += 2) {
                const unsigned int v = mb[(int)srcs[j] * 32 + c2];
                l0 += __uint_as_float(v << 16); h0 += __uint_as_float(v & 0xFFFF0000u);
            }
            accL[r] += (l0 + l1) + (l2 + l3);
            accH[r] += (h0 + h1) + (h2 + h3);
        }
        __syncthreads();
    }

#pragma unroll
    for (int r = 0; r < 4; r++) {
        accL[r] += __shfl_xor(accL[r], 32);
        accH[r] += __shfl_xor(accH[r], 32);
        const int nd = g * 32 + wave * 4 + r;
        if (nd < NN) {
            const int o = nd * CH + 2 * c2 + half;
            const float myv = half ? accH[r] : accL[r];
            out[o] = fmaxf(out[o] + myv, 0.f);
        }
    }
}

extern "C" void kernel_launch(void* const* d_in, const int* in_sizes, int n_in,
                              void* d_out, int out_size, void* d_ws, size_t ws_size,
                              hipStream_t stream)
{
    const float* x      = (const float*)d_in[0];
    const int*   edges  = (const int*)d_in[1];
    const float* Wself  = (const float*)d_in[2];
    const float* bself  = (const float*)d_in[3];
    const float* Wneigh = (const float*)d_in[4];
    const float* bneigh = (const float*)d_in[5];
    float* out = (float*)d_out;

    const int E = in_sizes[1] / 2;
    const int* rows = edges;        // edge_index[0] (sources)
    const int* cols = edges + E;    // edge_index[1] (destinations)

    char* ws_base = (char*)d_ws;
    unsigned int* msgb = (unsigned int*)(ws_base);         // 6.4 MB (bf16x2)
    int*   sorted = (int*)(ws_base + 12800000);            // 3.2 MB
    int*   bh     = (int*)(ws_base + 16000000);            // 800,256
    int*   bstart = (int*)(ws_base + 18100000);            // 6,256 (NB+1)

    const int bP = (NN + 31) / 32;   // 1563 proj blocks
    k_histproj<<<NBLK + bP, 256, 0, stream>>>(cols, bh, E, x, Wself, bself,
                                              Wneigh, bneigh, out, msgb);
    k_scanAB<<<1, 1024, 0, stream>>>(bh, bstart);
    kc_scatter<<<NBLK, 256, 0, stream>>>(rows, cols, bh, bstart, sorted, E);
    k_gfin2<<<NB, 512, 0, stream>>>(msgb, bstart, sorted, out);
}

// Round 11
// 80.067 us; speedup vs baseline: 2.2258x; 1.1921x over previous
//
#include <hip/hip_runtime.h>
#include <hip/hip_bf16.h>

#define NN 50000
#define CH 64
#define NB 1563          // ceil(NN/32) coarse buckets of 32 nodes
#define NBLK 256         // hist/scatter edge-chunk blocks (full machine)

// ---------- ws layout (bytes; ws is 256 MiB) ----------
// msgb      : [0, 6.4MB)               uint[NN*32] — bf16x2-packed x@Wn + bn
// sorted    : [12.8M, 16.0M)           int[E] packed (dst&31)<<16 | src, by bucket
// blockhist : [16.0M, +1,600,512)      int[NBLK][NB]
// btotal    : [17.7M, +6,252)          int[NB]
// bstart    : [18.1M, +6,256)          int[NB+1]

// ---------------- k_histproj: blocks [0,NBLK) = dest-bucket histogram;
//                  blocks [NBLK, NBLK+1563) = dual projection (proven round-8 body)
__global__ __launch_bounds__(256) void k_histproj(
    const int* __restrict__ cols, int* __restrict__ bh, int E,
    const float* __restrict__ x,
    const float* __restrict__ Wself, const float* __restrict__ bself,
    const float* __restrict__ Wneigh, const float* __restrict__ bneigh,
    float* __restrict__ hout, unsigned int* __restrict__ mout)
{
    __shared__ float smem[2 * CH * CH + 32 * CH];   // 40 KB, overlaid per role
    const int tid = threadIdx.x;

    if (blockIdx.x < NBLK) {
        // ---- histogram role
        int* lh = (int*)smem;
        const int b = blockIdx.x;
        for (int k = tid; k < NB; k += 256) lh[k] = 0;
        __syncthreads();
        const int chunk = (E + NBLK - 1) / NBLK;
        const int beg = b * chunk;
        const int fin = min(beg + chunk, E);
        for (int i = beg + tid; i < fin; i += 256)
            atomicAdd(&lh[cols[i] >> 5], 1);
        __syncthreads();
        for (int k = tid; k < NB; k += 256) bh[b * NB + k] = lh[k];
        return;
    }

    // ---- projection role
    float* ws = smem;
    float* wn = smem + CH * CH;
    float* xs = smem + 2 * CH * CH;
    const int node0 = (blockIdx.x - NBLK) * 32;

    for (int i = tid * 4; i < CH * CH; i += 256 * 4) {
        *(float4*)&ws[i] = *(const float4*)&Wself[i];
        *(float4*)&wn[i] = *(const float4*)&Wneigh[i];
    }
    for (int i = tid * 4; i < 32 * CH; i += 256 * 4) {
        const int nd = node0 + (i >> 6);
        float4 v = {0.f, 0.f, 0.f, 0.f};
        if (nd < NN) v = *(const float4*)&x[(size_t)nd * CH + (i & 63)];
        *(float4*)&xs[i] = v;
    }
    __syncthreads();

    const int lane = tid & 63;
    const int wave = tid >> 6;
    const int r0 = wave * 8;

    const float bsv = bself[lane];
    const float bnv = bneigh[lane];

    float accs[8], accn[8];
#pragma unroll
    for (int n = 0; n < 8; n++) { accs[n] = bsv; accn[n] = bnv; }

#pragma unroll 1
    for (int k4 = 0; k4 < CH; k4 += 4) {
        float4 xv[8];
#pragma unroll
        for (int n = 0; n < 8; n++)
            xv[n] = *(const float4*)&xs[(r0 + n) * CH + k4];
#pragma unroll
        for (int j = 0; j < 4; j++) {
            const float wsk = ws[(k4 + j) * CH + lane];
            const float wnk = wn[(k4 + j) * CH + lane];
#pragma unroll
            for (int n = 0; n < 8; n++) {
                const float xj = (j == 0) ? xv[n].x : (j == 1) ? xv[n].y
                               : (j == 2) ? xv[n].z : xv[n].w;
                accs[n] = fmaf(xj, wsk, accs[n]);
                accn[n] = fmaf(xj, wnk, accn[n]);
            }
        }
    }

#pragma unroll
    for (int n = 0; n < 8; n++) {
        const int nd = node0 + r0 + n;
        const float partner = __shfl_xor(accn[n], 1);
        if (nd < NN) {
            hout[(size_t)nd * CH + lane] = accs[n];
            if ((lane & 1) == 0) {
                __hip_bfloat162 p;
                p.x = __float2bfloat16(accn[n]);
                p.y = __float2bfloat16(partner);
                mout[(size_t)nd * 32 + (lane >> 1)] =
                    *reinterpret_cast<unsigned int*>(&p);
            }
        }
    }
}

// ---------------- k_scanA_par: one block per BUCKET; 256 threads load the 256
// per-chunk counts of this bucket (1 load/thread, TLP-hidden), block-scan,
// write back exclusive per-chunk bases + bucket total. No serial 256-chains.
__global__ __launch_bounds__(256) void k_scanA_par(int* __restrict__ bh,
                                                   int* __restrict__ btotal)
{
    __shared__ int wsum[4];
    const int k = blockIdx.x;            // bucket
    const int t = threadIdx.x;           // chunk (NBLK == 256)
    const int lane = t & 63, wid = t >> 6;

    const int v = bh[t * NB + k];
    int s = v;
#pragma unroll
    for (int d = 1; d < 64; d <<= 1) {
        int u = __shfl_up(s, d);
        if (lane >= d) s += u;
    }
    if (lane == 63) wsum[wid] = s;
    __syncthreads();
    if (t == 0) {
        int a = 0;
#pragma unroll
        for (int w = 0; w < 4; w++) { int u = wsum[w]; wsum[w] = a; a += u; }
        btotal[k] = a;
    }
    __syncthreads();
    bh[t * NB + k] = wsum[wid] + (s - v);   // exclusive base of chunk t in bucket k
}

// ---------------- k_scanB: bstart = exclusive_scan(btotal); bstart[NB] = E
__global__ __launch_bounds__(1024) void k_scanB(const int* __restrict__ cnt,
                                                int* __restrict__ off, int n)
{
    __shared__ int wsum[16];
    const int tid = threadIdx.x;
    const int lane = tid & 63, wid = tid >> 6;
    int carry = 0;
    for (int base = 0; base < n; base += 1024) {
        const int i = base + tid;
        const int v = (i < n) ? cnt[i] : 0;
        int s = v;
#pragma unroll
        for (int d = 1; d < 64; d <<= 1) {
            int t = __shfl_up(s, d);
            if (lane >= d) s += t;
        }
        if (lane == 63) wsum[wid] = s;
        __syncthreads();
        if (wid == 0 && lane < 16) {
            int wscan = wsum[lane];
#pragma unroll
            for (int d = 1; d < 16; d <<= 1) {
                int t = __shfl_up(wscan, d);
                if (lane >= d) wscan += t;
            }
            wsum[lane] = wscan;
        }
        __syncthreads();
        const int wave_off = (wid == 0) ? 0 : wsum[wid - 1];
        if (i < n) off[i] = carry + wave_off + (s - v);
        carry += wsum[15];
        __syncthreads();
    }
    if (tid == 0) off[n] = carry;    // = E
}

// ---------------- kc_scatter: place packed edges into bucket order; LDS atomics only
__global__ __launch_bounds__(256) void kc_scatter(
    const int* __restrict__ rows, const int* __restrict__ cols,
    const int* __restrict__ bh, const int* __restrict__ bstart,
    int* __restrict__ sorted, int E)
{
    __shared__ int lbase[NB];
    const int b = blockIdx.x, tid = threadIdx.x;
    for (int k = tid; k < NB; k += 256)
        lbase[k] = bstart[k] + bh[b * NB + k];
    __syncthreads();
    const int chunk = (E + NBLK - 1) / NBLK;
    const int beg = b * chunk;
    const int fin = min(beg + chunk, E);
    for (int i = beg + tid; i < fin; i += 256) {
        const int c = cols[i], r = rows[i];
        const int pos = atomicAdd(&lbase[c >> 5], 1);
        sorted[pos] = ((c & 31) << 16) | r;    // src < 50000 < 2^16
    }
}

// ---------------- k_gfin2: one block per bucket (32 nodes), 512 threads = 8 waves.
// Fine counting-sort in LDS, then bf16x2 gather (two edges per wave via the
// two 32-lane halves, 4-deep MLP per half); out = relu(h + sum).
__global__ __launch_bounds__(512) void k_gfin2(
    const unsigned int* __restrict__ mb, const int* __restrict__ bstart,
    const int* __restrict__ sorted, float* __restrict__ out)
{
    __shared__ int pairs[2048];
    __shared__ unsigned short srcs[2048];
    __shared__ int fh[32], foff[33], fcur[32];

    const int g = blockIdx.x;
    const int tid = threadIdx.x;
    const int lane = tid & 63, wave = tid >> 6;
    const int c2 = lane & 31;
    const int half = lane >> 5;
    const int base = bstart[g];
    const int ecnt = bstart[g + 1] - base;

    float accL[4], accH[4];
#pragma unroll
    for (int r = 0; r < 4; r++) { accL[r] = 0.f; accH[r] = 0.f; }

    for (int cb = 0; cb < ecnt; cb += 2048) {
        const int cn = min(2048, ecnt - cb);
        if (tid < 32) fh[tid] = 0;
        __syncthreads();
        for (int i = tid; i < cn; i += 512) {
            const int p = sorted[base + cb + i];
            pairs[i] = p;
            atomicAdd(&fh[p >> 16], 1);
        }
        __syncthreads();
        if (tid < 64) {
            const int v = (lane < 32) ? fh[lane] : 0;
            int s = v;
#pragma unroll
            for (int d = 1; d < 32; d <<= 1) {
                int t = __shfl_up(s, d);
                if (lane >= d) s += t;
            }
            if (lane < 32) { foff[lane] = s - v; fcur[lane] = s - v; }
            if (lane == 0) foff[32] = cn;
        }
        __syncthreads();
        for (int i = tid; i < cn; i += 512) {
            const int p = pairs[i];
            const int pos = atomicAdd(&fcur[p >> 16], 1);
            srcs[pos] = (unsigned short)(p & 0xFFFF);
        }
        __syncthreads();
#pragma unroll
        for (int r = 0; r < 4; r++) {
            const int nl = wave * 4 + r;
            const int j0 = foff[nl], j1 = foff[nl + 1];
            float l0 = 0.f, l1 = 0.f, l2 = 0.f, l3 = 0.f;
            float h0 = 0.f, h1 = 0.f, h2 = 0.f, h3 = 0.f;
            int j = j0 + half;
            for (; j + 6 < j1; j += 8) {
                const unsigned int v0 = mb[(int)srcs[j]     * 32 + c2];
                const unsigned int v1 = mb[(int)srcs[j + 2] * 32 + c2];
                const unsigned int v2 = mb[(int)srcs[j + 4] * 32 + c2];
                const unsigned int v3 = mb[(int)srcs[j + 6] * 32 + c2];
                l0 += __uint_as_float(v0 << 16); h0 += __uint_as_float(v0 & 0xFFFF0000u);
                l1 += __uint_as_float(v1 << 16); h1 += __uint_as_float(v1 & 0xFFFF0000u);
                l2 += __uint_as_float(v2 << 16); h2 += __uint_as_float(v2 & 0xFFFF0000u);
                l3 += __uint_as_float(v3 << 16); h3 += __uint_as_float(v3 & 0xFFFF0000u);
            }
            for (; j < j1; j += 2) {
                const unsigned int v = mb[(int)srcs[j] * 32 + c2];
                l0 += __uint_as_float(v << 16); h0 += __uint_as_float(v & 0xFFFF0000u);
            }
            accL[r] += (l0 + l1) + (l2 + l3);
            accH[r] += (h0 + h1) + (h2 + h3);
        }
        __syncthreads();
    }

#pragma unroll
    for (int r = 0; r < 4; r++) {
        accL[r] += __shfl_xor(accL[r], 32);
        accH[r] += __shfl_xor(accH[r], 32);
        const int nd = g * 32 + wave * 4 + r;
        if (nd < NN) {
            const int o = nd * CH + 2 * c2 + half;
            const float myv = half ? accH[r] : accL[r];
            out[o] = fmaxf(out[o] + myv, 0.f);
        }
    }
}

extern "C" void kernel_launch(void* const* d_in, const int* in_sizes, int n_in,
                              void* d_out, int out_size, void* d_ws, size_t ws_size,
                              hipStream_t stream)
{
    const float* x      = (const float*)d_in[0];
    const int*   edges  = (const int*)d_in[1];
    const float* Wself  = (const float*)d_in[2];
    const float* bself  = (const float*)d_in[3];
    const float* Wneigh = (const float*)d_in[4];
    const float* bneigh = (const float*)d_in[5];
    float* out = (float*)d_out;

    const int E = in_sizes[1] / 2;
    const int* rows = edges;        // edge_index[0] (sources)
    const int* cols = edges + E;    // edge_index[1] (destinations)

    char* ws_base = (char*)d_ws;
    unsigned int* msgb = (unsigned int*)(ws_base);         // 6.4 MB (bf16x2)
    int*   sorted = (int*)(ws_base + 12800000);            // 3.2 MB
    int*   bh     = (int*)(ws_base + 16000000);            // 1,600,512
    int*   btotal = (int*)(ws_base + 17700000);            // 6,252
    int*   bstart = (int*)(ws_base + 18100000);            // 6,256 (NB+1)

    const int bP = (NN + 31) / 32;   // 1563 proj blocks
    k_histproj<<<NBLK + bP, 256, 0, stream>>>(cols, bh, E, x, Wself, bself,
                                              Wneigh, bneigh, out, msgb);
    k_scanA_par<<<NB, 256, 0, stream>>>(bh, btotal);
    k_scanB<<<1, 1024, 0, stream>>>(btotal, bstart, NB);
    kc_scatter<<<NBLK, 256, 0, stream>>>(rows, cols, bh, bstart, sorted, E);
    k_gfin2<<<NB, 512, 0, stream>>>(msgb, bstart, sorted, out);
}

// Round 12
// 59.499 us; speedup vs baseline: 2.9952x; 1.3457x over previous
//
#include <hip/hip_runtime.h>
#include <hip/hip_bf16.h>

#define NN 50000
#define CH 64
#define NB 1563          // ceil(NN/32) coarse buckets of 32 nodes
#define NBLK 256         // sort-role blocks (1 edge-chunk each)

// ---------- ws layout (bytes; ws is 256 MiB) ----------
// msgb   : [0, 6.4MB)        uint[NN*32] — bf16x2-packed x@Wn + bn
// sorted : [12.8M, +3.2MB)   int[E] packed (dst&31)<<16|src, BLOCK-MAJOR
//                            (block b's chunk contiguous, bucket-sorted inside)
// off    : [16.0M, +1.6MB)   int[NBLK][NB+1] per-block bucket offsets in chunk

// ---------------- k_main: blocks [0,NBLK) = local counting sort of edge chunk;
//                  blocks [NBLK, NBLK+1563) = dual projection (proven body)
__global__ __launch_bounds__(256) void k_main(
    const int* __restrict__ rows, const int* __restrict__ cols,
    int* __restrict__ sorted, int* __restrict__ off, int E,
    const float* __restrict__ x,
    const float* __restrict__ Wself, const float* __restrict__ bself,
    const float* __restrict__ Wneigh, const float* __restrict__ bneigh,
    float* __restrict__ hout, unsigned int* __restrict__ mout)
{
    __shared__ float smem[2 * CH * CH + 32 * CH];   // 40 KB union
    __shared__ int wsum[8];
    const int tid = threadIdx.x;
    const int lane = tid & 63, wid = tid >> 6;

    if (blockIdx.x < NBLK) {
        // ---- sort role: chunk [beg,fin) -> sorted[beg..], off[b][*]
        int* lh     = (int*)smem;                 // [NB] hist, later cursors
        int* loff   = (int*)smem + NB;            // [NB+1] exclusive offsets
        int* staged = (int*)smem + 2 * NB + 1;    // [chunk] sorted-in-LDS edges
        const int b = blockIdx.x;
        const int chunk = (E + NBLK - 1) / NBLK;  // 3125 for E=800000
        const int beg = b * chunk;
        const int fin = min(beg + chunk, E);

        for (int k = tid; k < NB; k += 256) lh[k] = 0;
        __syncthreads();
        for (int i = beg + tid; i < fin; i += 256)
            atomicAdd(&lh[cols[i] >> 5], 1);
        __syncthreads();

        // exclusive LDS scan lh[0..NB) -> loff, loff[NB]=total
        int carry = 0;
        for (int base = 0; base < NB; base += 256) {
            const int i = base + tid;
            const int v = (i < NB) ? lh[i] : 0;
            int s = v;
#pragma unroll
            for (int d = 1; d < 64; d <<= 1) {
                int t = __shfl_up(s, d);
                if (lane >= d) s += t;
            }
            if (lane == 63) wsum[wid] = s;
            __syncthreads();
            if (tid == 0) {
                int a = 0;
#pragma unroll
                for (int w = 0; w < 4; w++) { int t = wsum[w]; wsum[w] = a; a += t; }
                wsum[4] = a;
            }
            __syncthreads();
            if (i < NB) loff[i] = carry + wsum[wid] + (s - v);
            carry += wsum[4];
            __syncthreads();
        }
        if (tid == 0) loff[NB] = carry;
        __syncthreads();

        // cursors (reuse lh), place pass, coalesced flush, off-table write
        for (int k = tid; k < NB; k += 256) lh[k] = loff[k];
        __syncthreads();
        for (int i = beg + tid; i < fin; i += 256) {
            const int c = cols[i], r = rows[i];
            const int pos = atomicAdd(&lh[c >> 5], 1);
            staged[pos] = ((c & 31) << 16) | r;    // src < 50000 < 2^16
        }
        __syncthreads();
        const int cnt = fin - beg;
        for (int i = tid; i < cnt; i += 256) sorted[beg + i] = staged[i];
        for (int k = tid; k < NB + 1; k += 256) off[b * (NB + 1) + k] = loff[k];
        return;
    }

    // ---- projection role (proven round-8 body)
    float* ws = smem;
    float* wn = smem + CH * CH;
    float* xs = smem + 2 * CH * CH;
    const int node0 = (blockIdx.x - NBLK) * 32;

    for (int i = tid * 4; i < CH * CH; i += 256 * 4) {
        *(float4*)&ws[i] = *(const float4*)&Wself[i];
        *(float4*)&wn[i] = *(const float4*)&Wneigh[i];
    }
    for (int i = tid * 4; i < 32 * CH; i += 256 * 4) {
        const int nd = node0 + (i >> 6);
        float4 v = {0.f, 0.f, 0.f, 0.f};
        if (nd < NN) v = *(const float4*)&x[(size_t)nd * CH + (i & 63)];
        *(float4*)&xs[i] = v;
    }
    __syncthreads();

    const int r0 = wid * 8;
    const float bsv = bself[lane];
    const float bnv = bneigh[lane];

    float accs[8], accn[8];
#pragma unroll
    for (int n = 0; n < 8; n++) { accs[n] = bsv; accn[n] = bnv; }

#pragma unroll 1
    for (int k4 = 0; k4 < CH; k4 += 4) {
        float4 xv[8];
#pragma unroll
        for (int n = 0; n < 8; n++)
            xv[n] = *(const float4*)&xs[(r0 + n) * CH + k4];
#pragma unroll
        for (int j = 0; j < 4; j++) {
            const float wsk = ws[(k4 + j) * CH + lane];
            const float wnk = wn[(k4 + j) * CH + lane];
#pragma unroll
            for (int n = 0; n < 8; n++) {
                const float xj = (j == 0) ? xv[n].x : (j == 1) ? xv[n].y
                               : (j == 2) ? xv[n].z : xv[n].w;
                accs[n] = fmaf(xj, wsk, accs[n]);
                accn[n] = fmaf(xj, wnk, accn[n]);
            }
        }
    }

#pragma unroll
    for (int n = 0; n < 8; n++) {
        const int nd = node0 + r0 + n;
        const float partner = __shfl_xor(accn[n], 1);
        if (nd < NN) {
            hout[(size_t)nd * CH + lane] = accs[n];
            if ((lane & 1) == 0) {
                __hip_bfloat162 p;
                p.x = __float2bfloat16(accn[n]);
                p.y = __float2bfloat16(partner);
                mout[(size_t)nd * 32 + (lane >> 1)] =
                    *reinterpret_cast<unsigned int*>(&p);
            }
        }
    }
}

// ---------------- k_gfin3: one block per bucket (32 nodes), 512 threads.
// Stage the bucket's edges from the 256 block-major segments into LDS,
// fine counting-sort by the 32 local dests, bf16x2 gather, relu-finish.
__global__ __launch_bounds__(512) void k_gfin3(
    const unsigned int* __restrict__ mb, const int* __restrict__ off,
    const int* __restrict__ sorted, float* __restrict__ out, int E)
{
    __shared__ int pairs[4096];
    __shared__ unsigned short srcs[4096];
    __shared__ int segoff[257];
    __shared__ int fh[32], foff[33], fcur[32];
    __shared__ int wsum[8];

    const int g = blockIdx.x;
    const int tid = threadIdx.x;
    const int lane = tid & 63, wave = tid >> 6;
    const int chunk = (E + NBLK - 1) / NBLK;

    // ---- segment-count scan (threads 0..255 own segment = source block)
    int s0 = 0, mycnt = 0;
    if (tid < 256) {
        s0    = off[tid * (NB + 1) + g];
        mycnt = off[tid * (NB + 1) + g + 1] - s0;
    }
    {
        int s = mycnt;
#pragma unroll
        for (int d = 1; d < 64; d <<= 1) {
            int t = __shfl_up(s, d);
            if (lane >= d) s += t;
        }
        if (tid < 256 && lane == 63) wsum[wave] = s;
        __syncthreads();
        if (tid == 0) {
            int a = 0;
#pragma unroll
            for (int w = 0; w < 4; w++) { int t = wsum[w]; wsum[w] = a; a += t; }
            wsum[4] = a;
        }
        __syncthreads();
        if (tid < 256) {
            const int myoff = wsum[wave] + (s - mycnt);
            segoff[tid] = myoff;
            // ---- copy my segment into pairs[] (bucket cap 4096: P(overflow)~0)
            const int src = tid * chunk + s0;
            for (int j = 0; j < mycnt; j++) {
                const int dst = myoff + j;
                if (dst < 4096) pairs[dst] = sorted[src + j];
            }
        }
        if (tid == 0) segoff[256] = wsum[4];
    }
    __syncthreads();
    const int cn = min(segoff[256], 4096);

    // ---- fine counting-sort by local dest (LDS)
    if (tid < 32) fh[tid] = 0;
    __syncthreads();
    for (int i = tid; i < cn; i += 512)
        atomicAdd(&fh[pairs[i] >> 16], 1);
    __syncthreads();
    if (tid < 64) {
        const int v = (lane < 32) ? fh[lane] : 0;
        int s = v;
#pragma unroll
        for (int d = 1; d < 32; d <<= 1) {
            int t = __shfl_up(s, d);
            if (lane >= d) s += t;
        }
        if (lane < 32) { foff[lane] = s - v; fcur[lane] = s - v; }
        if (lane == 0) foff[32] = cn;
    }
    __syncthreads();
    for (int i = tid; i < cn; i += 512) {
        const int p = pairs[i];
        const int pos = atomicAdd(&fcur[p >> 16], 1);
        srcs[pos] = (unsigned short)(p & 0xFFFF);
    }
    __syncthreads();

    // ---- gather: wave handles 4 local nodes; two 32-lane halves = 2 edges at
    // once (c2 = channel pair, half = edge parity), 4-deep MLP per half
    const int c2 = lane & 31;
    const int half = lane >> 5;
    float accL[4], accH[4];
#pragma unroll
    for (int r = 0; r < 4; r++) { accL[r] = 0.f; accH[r] = 0.f; }

#pragma unroll
    for (int r = 0; r < 4; r++) {
        const int nl = wave * 4 + r;
        const int j0 = foff[nl], j1 = foff[nl + 1];
        float l0 = 0.f, l1 = 0.f, l2 = 0.f, l3 = 0.f;
        float h0 = 0.f, h1 = 0.f, h2 = 0.f, h3 = 0.f;
        int j = j0 + half;
        for (; j + 6 < j1; j += 8) {
            const unsigned int v0 = mb[(int)srcs[j]     * 32 + c2];
            const unsigned int v1 = mb[(int)srcs[j + 2] * 32 + c2];
            const unsigned int v2 = mb[(int)srcs[j + 4] * 32 + c2];
            const unsigned int v3 = mb[(int)srcs[j + 6] * 32 + c2];
            l0 += __uint_as_float(v0 << 16); h0 += __uint_as_float(v0 & 0xFFFF0000u);
            l1 += __uint_as_float(v1 << 16); h1 += __uint_as_float(v1 & 0xFFFF0000u);
            l2 += __uint_as_float(v2 << 16); h2 += __uint_as_float(v2 & 0xFFFF0000u);
            l3 += __uint_as_float(v3 << 16); h3 += __uint_as_float(v3 & 0xFFFF0000u);
        }
        for (; j < j1; j += 2) {
            const unsigned int v = mb[(int)srcs[j] * 32 + c2];
            l0 += __uint_as_float(v << 16); h0 += __uint_as_float(v & 0xFFFF0000u);
        }
        accL[r] += (l0 + l1) + (l2 + l3);
        accH[r] += (h0 + h1) + (h2 + h3);
    }

#pragma unroll
    for (int r = 0; r < 4; r++) {
        accL[r] += __shfl_xor(accL[r], 32);
        accH[r] += __shfl_xor(accH[r], 32);
        const int nd = g * 32 + wave * 4 + r;
        if (nd < NN) {
            const int o = nd * CH + 2 * c2 + half;
            const float myv = half ? accH[r] : accL[r];
            out[o] = fmaxf(out[o] + myv, 0.f);
        }
    }
}

extern "C" void kernel_launch(void* const* d_in, const int* in_sizes, int n_in,
                              void* d_out, int out_size, void* d_ws, size_t ws_size,
                              hipStream_t stream)
{
    const float* x      = (const float*)d_in[0];
    const int*   edges  = (const int*)d_in[1];
    const float* Wself  = (const float*)d_in[2];
    const float* bself  = (const float*)d_in[3];
    const float* Wneigh = (const float*)d_in[4];
    const float* bneigh = (const float*)d_in[5];
    float* out = (float*)d_out;

    const int E = in_sizes[1] / 2;
    const int* rows = edges;        // edge_index[0] (sources)
    const int* cols = edges + E;    // edge_index[1] (destinations)

    char* ws_base = (char*)d_ws;
    unsigned int* msgb = (unsigned int*)(ws_base);         // 6.4 MB (bf16x2)
    int*   sorted = (int*)(ws_base + 12800000);            // 3.2 MB block-major
    int*   off    = (int*)(ws_base + 16000000);            // 256*(NB+1)*4 = 1.6 MB

    const int bP = (NN + 31) / 32;   // 1563 proj blocks
    k_main<<<NBLK + bP, 256, 0, stream>>>(rows, cols, sorted, off, E,
                                          x, Wself, bself, Wneigh, bneigh,
                                          out, msgb);
    k_gfin3<<<NB, 512, 0, stream>>>(msgb, off, sorted, out, E);
}

// Round 13
// 58.506 us; speedup vs baseline: 3.0460x; 1.0170x over previous
//
#include <hip/hip_runtime.h>
#include <hip/hip_bf16.h>

#define NN 50000
#define CH 64
#define NB 1563          // ceil(NN/32) coarse buckets of 32 nodes
#define NBLK 256         // sort-role blocks (1 edge-chunk each)

typedef __attribute__((ext_vector_type(8))) short short8;  // 8 bf16 (4 VGPRs)
typedef __attribute__((ext_vector_type(4))) float f32x4;   // MFMA 16x16 acc

__device__ __forceinline__ unsigned short f2bf(float f) {
    __hip_bfloat16 h = __float2bfloat16(f);
    return *reinterpret_cast<unsigned short*>(&h);
}

// ---------- ws layout (bytes; ws is 256 MiB) ----------
// msgb   : [0, 6.4MB)        uint[NN*32] — bf16x2-packed x@Wn + bn
// sorted : [12.8M, +3.2MB)   int[E] packed (dst&31)<<16|src, BLOCK-MAJOR
// off    : [16.0M, +1.6MB)   int[NBLK][NB+1] per-block bucket offsets
// wfrag  : [17.7M, +16KB)    bf16 fragment-major [ni(8)][kstep(2)][lane(64)][8]

// ---------------- k_prep: W -> fragment-major bf16 (B-operand of MFMA)
// B[k][n] = n<64 ? Wself[k][n] : Wneigh[k][n-64]; frag elem j = k0+j.
__global__ __launch_bounds__(128) void k_prep(
    const float* __restrict__ Ws, const float* __restrict__ Wn,
    uint4* __restrict__ wfrag)
{
    const int ni = blockIdx.x;        // 0..7 (output 16-col tile)
    const int t  = threadIdx.x;       // 0..127
    const int ks = t >> 6, l = t & 63;
    const int c16 = l & 15, kg = l >> 4;
    const int k0 = ks * 32 + kg * 8;
    const float* B = (ni < 4) ? Ws : Wn;
    const int c = ((ni < 4) ? ni : ni - 4) * 16 + c16;
    unsigned int w4[4];
#pragma unroll
    for (int jj = 0; jj < 4; jj++) {
        const unsigned short lo = f2bf(B[(k0 + 2 * jj)     * CH + c]);
        const unsigned short hi = f2bf(B[(k0 + 2 * jj + 1) * CH + c]);
        w4[jj] = (unsigned int)lo | ((unsigned int)hi << 16);
    }
    wfrag[(ni * 2 + ks) * 64 + l] = make_uint4(w4[0], w4[1], w4[2], w4[3]);
}

// ---------------- k_main: blocks [0,NBLK) = local counting sort of edge chunk;
//                  blocks [NBLK, NBLK+1563) = MFMA dual projection (no LDS)
__global__ __launch_bounds__(256) void k_main(
    const int* __restrict__ rows, const int* __restrict__ cols,
    int* __restrict__ sorted, int* __restrict__ off, int E,
    const float* __restrict__ x,
    const float* __restrict__ bself, const float* __restrict__ bneigh,
    const short8* __restrict__ wfrag,
    float* __restrict__ hout, unsigned int* __restrict__ mout)
{
    __shared__ int smem[2 * NB + 1 + 3200];   // sort role only (~25.3 KB)
    __shared__ int wsum[8];
    const int tid = threadIdx.x;
    const int lane = tid & 63, wid = tid >> 6;

    if (blockIdx.x < NBLK) {
        // ---- sort role (proven round-12 body)
        int* lh     = smem;                   // [NB] hist, later cursors
        int* loff   = smem + NB;              // [NB+1] exclusive offsets
        int* staged = smem + 2 * NB + 1;      // [chunk<=3200]
        const int b = blockIdx.x;
        const int chunk = (E + NBLK - 1) / NBLK;
        const int beg = b * chunk;
        const int fin = min(beg + chunk, E);

        for (int k = tid; k < NB; k += 256) lh[k] = 0;
        __syncthreads();
        for (int i = beg + tid; i < fin; i += 256)
            atomicAdd(&lh[cols[i] >> 5], 1);
        __syncthreads();

        int carry = 0;
        for (int base = 0; base < NB; base += 256) {
            const int i = base + tid;
            const int v = (i < NB) ? lh[i] : 0;
            int s = v;
#pragma unroll
            for (int d = 1; d < 64; d <<= 1) {
                int t = __shfl_up(s, d);
                if (lane >= d) s += t;
            }
            if (lane == 63) wsum[wid] = s;
            __syncthreads();
            if (tid == 0) {
                int a = 0;
#pragma unroll
                for (int w = 0; w < 4; w++) { int t = wsum[w]; wsum[w] = a; a += t; }
                wsum[4] = a;
            }
            __syncthreads();
            if (i < NB) loff[i] = carry + wsum[wid] + (s - v);
            carry += wsum[4];
            __syncthreads();
        }
        if (tid == 0) loff[NB] = carry;
        __syncthreads();

        for (int k = tid; k < NB; k += 256) lh[k] = loff[k];
        __syncthreads();
        for (int i = beg + tid; i < fin; i += 256) {
            const int c = cols[i], r = rows[i];
            const int pos = atomicAdd(&lh[c >> 5], 1);
            staged[pos] = ((c & 31) << 16) | r;    // src < 50000 < 2^16
        }
        __syncthreads();
        const int cnt = fin - beg;
        for (int i = tid; i < cnt; i += 256) sorted[beg + i] = staged[i];
        for (int k = tid; k < NB + 1; k += 256) off[b * (NB + 1) + k] = loff[k];
        return;
    }

    // ---- projection role: C[32x128] = xtile @ [Ws|Wn] via 16x16x32 bf16 MFMA
    const int node0 = (blockIdx.x - NBLK) * 32;
    const int mi = wid & 1;               // output row 16-tile
    const int niBase = (wid >> 1) * 4;    // 4 col-tiles per wave
    const int c16 = lane & 15, kg = lane >> 4;

    // A-frags straight from global x (8 consecutive f32 per lane), clamped row
    int arow = node0 + mi * 16 + c16;
    if (arow > NN - 1) arow = NN - 1;
    const size_t abase = (size_t)arow * CH;
    short8 af[2];
#pragma unroll
    for (int ks = 0; ks < 2; ks++) {
        const float4 p = *(const float4*)&x[abase + ks * 32 + kg * 8];
        const float4 q = *(const float4*)&x[abase + ks * 32 + kg * 8 + 4];
        short8 a;
        a[0] = (short)f2bf(p.x); a[1] = (short)f2bf(p.y);
        a[2] = (short)f2bf(p.z); a[3] = (short)f2bf(p.w);
        a[4] = (short)f2bf(q.x); a[5] = (short)f2bf(q.y);
        a[6] = (short)f2bf(q.z); a[7] = (short)f2bf(q.w);
        af[ks] = a;
    }

    f32x4 acc[4];
#pragma unroll
    for (int t2 = 0; t2 < 4; t2++) {
        const int ni = niBase + t2;
        const float bias = (ni < 4) ? bself[ni * 16 + c16]
                                    : bneigh[(ni - 4) * 16 + c16];
        acc[t2] = (f32x4){bias, bias, bias, bias};   // bias uniform over rows
#pragma unroll
        for (int ks = 0; ks < 2; ks++) {
            const short8 bf = wfrag[(ni * 2 + ks) * 64 + lane];
            acc[t2] = __builtin_amdgcn_mfma_f32_16x16x32_bf16(af[ks], bf,
                                                              acc[t2], 0, 0, 0);
        }
    }

    // epilogue: C/D layout col=lane&15, row=(lane>>4)*4+r (verified mapping)
#pragma unroll
    for (int t2 = 0; t2 < 4; t2++) {
        const int ni = niBase + t2;
#pragma unroll
        for (int r = 0; r < 4; r++) {
            const int node = node0 + mi * 16 + kg * 4 + r;
            const float v = acc[t2][r];
            if (ni < 4) {                      // h -> out (f32)
                if (node < NN)
                    hout[(size_t)node * CH + ni * 16 + c16] = v;
            } else {                           // msg -> bf16x2 pack
                const float partner = __shfl_xor(v, 1);
                if (node < NN && (lane & 1) == 0) {
                    const unsigned int pk = (unsigned int)f2bf(v)
                                          | ((unsigned int)f2bf(partner) << 16);
                    mout[(size_t)node * 32 + (ni - 4) * 8 + (c16 >> 1)] = pk;
                }
            }
        }
    }
}

// ---------------- k_gfin3: one block per bucket (32 nodes), 512 threads.
// (unchanged from round 12)
__global__ __launch_bounds__(512) void k_gfin3(
    const unsigned int* __restrict__ mb, const int* __restrict__ off,
    const int* __restrict__ sorted, float* __restrict__ out, int E)
{
    __shared__ int pairs[4096];
    __shared__ unsigned short srcs[4096];
    __shared__ int segoff[257];
    __shared__ int fh[32], foff[33], fcur[32];
    __shared__ int wsum[8];

    const int g = blockIdx.x;
    const int tid = threadIdx.x;
    const int lane = tid & 63, wave = tid >> 6;
    const int chunk = (E + NBLK - 1) / NBLK;

    int s0 = 0, mycnt = 0;
    if (tid < 256) {
        s0    = off[tid * (NB + 1) + g];
        mycnt = off[tid * (NB + 1) + g + 1] - s0;
    }
    {
        int s = mycnt;
#pragma unroll
        for (int d = 1; d < 64; d <<= 1) {
            int t = __shfl_up(s, d);
            if (lane >= d) s += t;
        }
        if (tid < 256 && lane == 63) wsum[wave] = s;
        __syncthreads();
        if (tid == 0) {
            int a = 0;
#pragma unroll
            for (int w = 0; w < 4; w++) { int t = wsum[w]; wsum[w] = a; a += t; }
            wsum[4] = a;
        }
        __syncthreads();
        if (tid < 256) {
            const int myoff = wsum[wave] + (s - mycnt);
            segoff[tid] = myoff;
            const int src = tid * chunk + s0;
            for (int j = 0; j < mycnt; j++) {
                const int dst = myoff + j;
                if (dst < 4096) pairs[dst] = sorted[src + j];
            }
        }
        if (tid == 0) segoff[256] = wsum[4];
    }
    __syncthreads();
    const int cn = min(segoff[256], 4096);

    if (tid < 32) fh[tid] = 0;
    __syncthreads();
    for (int i = tid; i < cn; i += 512)
        atomicAdd(&fh[pairs[i] >> 16], 1);
    __syncthreads();
    if (tid < 64) {
        const int v = (lane < 32) ? fh[lane] : 0;
        int s = v;
#pragma unroll
        for (int d = 1; d < 32; d <<= 1) {
            int t = __shfl_up(s, d);
            if (lane >= d) s += t;
        }
        if (lane < 32) { foff[lane] = s - v; fcur[lane] = s - v; }
        if (lane == 0) foff[32] = cn;
    }
    __syncthreads();
    for (int i = tid; i < cn; i += 512) {
        const int p = pairs[i];
        const int pos = atomicAdd(&fcur[p >> 16], 1);
        srcs[pos] = (unsigned short)(p & 0xFFFF);
    }
    __syncthreads();

    const int c2 = lane & 31;
    const int half = lane >> 5;
    float accL[4], accH[4];
#pragma unroll
    for (int r = 0; r < 4; r++) { accL[r] = 0.f; accH[r] = 0.f; }

#pragma unroll
    for (int r = 0; r < 4; r++) {
        const int nl = wave * 4 + r;
        const int j0 = foff[nl], j1 = foff[nl + 1];
        float l0 = 0.f, l1 = 0.f, l2 = 0.f, l3 = 0.f;
        float h0 = 0.f, h1 = 0.f, h2 = 0.f, h3 = 0.f;
        int j = j0 + half;
        for (; j + 6 < j1; j += 8) {
            const unsigned int v0 = mb[(int)srcs[j]     * 32 + c2];
            const unsigned int v1 = mb[(int)srcs[j + 2] * 32 + c2];
            const unsigned int v2 = mb[(int)srcs[j + 4] * 32 + c2];
            const unsigned int v3 = mb[(int)srcs[j + 6] * 32 + c2];
            l0 += __uint_as_float(v0 << 16); h0 += __uint_as_float(v0 & 0xFFFF0000u);
            l1 += __uint_as_float(v1 << 16); h1 += __uint_as_float(v1 & 0xFFFF0000u);
            l2 += __uint_as_float(v2 << 16); h2 += __uint_as_float(v2 & 0xFFFF0000u);
            l3 += __uint_as_float(v3 << 16); h3 += __uint_as_float(v3 & 0xFFFF0000u);
        }
        for (; j < j1; j += 2) {
            const unsigned int v = mb[(int)srcs[j] * 32 + c2];
            l0 += __uint_as_float(v << 16); h0 += __uint_as_float(v & 0xFFFF0000u);
        }
        accL[r] += (l0 + l1) + (l2 + l3);
        accH[r] += (h0 + h1) + (h2 + h3);
    }

#pragma unroll
    for (int r = 0; r < 4; r++) {
        accL[r] += __shfl_xor(accL[r], 32);
        accH[r] += __shfl_xor(accH[r], 32);
        const int nd = g * 32 + wave * 4 + r;
        if (nd < NN) {
            const int o = nd * CH + 2 * c2 + half;
            const float myv = half ? accH[r] : accL[r];
            out[o] = fmaxf(out[o] + myv, 0.f);
        }
    }
}

extern "C" void kernel_launch(void* const* d_in, const int* in_sizes, int n_in,
                              void* d_out, int out_size, void* d_ws, size_t ws_size,
                              hipStream_t stream)
{
    const float* x      = (const float*)d_in[0];
    const int*   edges  = (const int*)d_in[1];
    const float* Wself  = (const float*)d_in[2];
    const float* bself  = (const float*)d_in[3];
    const float* Wneigh = (const float*)d_in[4];
    const float* bneigh = (const float*)d_in[5];
    float* out = (float*)d_out;

    const int E = in_sizes[1] / 2;
    const int* rows = edges;        // edge_index[0] (sources)
    const int* cols = edges + E;    // edge_index[1] (destinations)

    char* ws_base = (char*)d_ws;
    unsigned int* msgb = (unsigned int*)(ws_base);         // 6.4 MB (bf16x2)
    int*   sorted = (int*)(ws_base + 12800000);            // 3.2 MB block-major
    int*   off    = (int*)(ws_base + 16000000);            // 1.6 MB
    uint4* wfrag  = (uint4*)(ws_base + 17700000);          // 16 KB frag-major W

    k_prep<<<8, 128, 0, stream>>>(Wself, Wneigh, wfrag);

    const int bP = (NN + 31) / 32;   // 1563 proj blocks
    k_main<<<NBLK + bP, 256, 0, stream>>>(rows, cols, sorted, off, E,
                                          x, bself, bneigh,
                                          (const short8*)wfrag, out, msgb);
    k_gfin3<<<NB, 512, 0, stream>>>(msgb, off, sorted, out, E);
}